// Round 2
// baseline (611.281 us; speedup 1.0000x reference)
//
#include <hip/hip_runtime.h>

typedef unsigned int u32;
typedef unsigned short u16;

#define N_TOK 1024
#define D_DIM 2048
#define F_DIM 5632
#define E_NUM 8
#define R_DIM 16
#define LSCALE 2.0f
#define FT 256            // f-columns per act_v2 block
#define NT (F_DIM / FT)   // 22 F-tiles
#define TC 4              // token chunks per expert

typedef __bf16 bf16x8 __attribute__((ext_vector_type(8)));
typedef float f32x4 __attribute__((ext_vector_type(4)));
typedef u16 u16x8 __attribute__((ext_vector_type(8)));

__device__ inline u16 f2bf(float f) {
    u32 u = __builtin_bit_cast(u32, f);
    u32 r = (u + 0x7fffu + ((u >> 16) & 1u)) >> 16;
    return (u16)r;
}
__device__ inline float bf2f(u16 h) {
    u32 u = ((u32)h) << 16;
    return __builtin_bit_cast(float, u);
}

// ---------------- fp32 -> bf16 conversion (vectorized) ----------------
__global__ __launch_bounds__(256) void cvt_f32_bf16(const float* __restrict__ src,
                                                    u16* __restrict__ dst, int n4) {
    int i = blockIdx.x * 256 + threadIdx.x;
    if (i >= n4) return;
    float4 v = ((const float4*)src)[i];
    union { u16 h[4]; ushort4 u4; } o;
    o.h[0] = f2bf(v.x); o.h[1] = f2bf(v.y); o.h[2] = f2bf(v.z); o.h[3] = f2bf(v.w);
    ((ushort4*)dst)[i] = o.u4;
}

// ---------------- A2 (E,R,F) fp32 -> A2t (E,F,R) bf16 ----------------
__global__ __launch_bounds__(256) void a2_transpose(const float* __restrict__ A2,
                                                    u16* __restrict__ A2t) {
    int e = blockIdx.y;
    int f = blockIdx.x * 256 + threadIdx.x;
    u16 row[16];
#pragma unroll
    for (int r = 0; r < 16; ++r)
        row[r] = f2bf(A2[((size_t)e * R_DIM + r) * F_DIM + f]);
    u16* dst = A2t + ((size_t)e * F_DIM + f) * 16;
#pragma unroll
    for (int q = 0; q < 2; ++q)
        ((ulonglong2*)dst)[q] = ((ulonglong2*)row)[q];
}

// ---------------- router: logits + softmax + top2 ----------------
__global__ __launch_bounds__(256) void router_kernel(const float* __restrict__ x,
                                                     const float* __restrict__ gw,
                                                     float* __restrict__ logits,
                                                     int* __restrict__ ridx,
                                                     float* __restrict__ rw) {
    int n = blockIdx.x;
    int tid = threadIdx.x;
    float part[E_NUM];
#pragma unroll
    for (int e = 0; e < E_NUM; ++e) part[e] = 0.f;
    const float* xr = x + (size_t)n * D_DIM;
    for (int d = tid; d < D_DIM; d += 256) {
        float xv = xr[d];
#pragma unroll
        for (int e = 0; e < E_NUM; ++e) part[e] += xv * gw[e * D_DIM + d];
    }
    __shared__ float sh[E_NUM][256];
#pragma unroll
    for (int e = 0; e < E_NUM; ++e) sh[e][tid] = part[e];
    __syncthreads();
    for (int off = 128; off > 0; off >>= 1) {
        if (tid < off) {
#pragma unroll
            for (int e = 0; e < E_NUM; ++e) sh[e][tid] += sh[e][tid + off];
        }
        __syncthreads();
    }
    if (tid == 0) {
        float lg[E_NUM], p[E_NUM];
        float mx = -1e30f;
        for (int e = 0; e < E_NUM; ++e) {
            lg[e] = sh[e][0];
            logits[n * E_NUM + e] = lg[e];
            if (lg[e] > mx) mx = lg[e];
        }
        float s = 0.f;
        for (int e = 0; e < E_NUM; ++e) { p[e] = expf(lg[e] - mx); s += p[e]; }
        for (int e = 0; e < E_NUM; ++e) p[e] /= s;
        int i1 = 0;
        for (int e = 1; e < E_NUM; ++e) if (p[e] > p[i1]) i1 = e;
        int i2 = (i1 == 0) ? 1 : 0;
        for (int e = 0; e < E_NUM; ++e) if (e != i1 && p[e] > p[i2]) i2 = e;
        float t = p[i1] + p[i2];
        ridx[n * 2] = i1; ridx[n * 2 + 1] = i2;
        rw[n * 2] = p[i1] / t; rw[n * 2 + 1] = p[i2] / t;
    }
}

// ---------------- expert token-list build ----------------
__global__ __launch_bounds__(64) void zero_counts(int* counts) {
    if (threadIdx.x < E_NUM) counts[threadIdx.x] = 0;
}
__global__ __launch_bounds__(256) void build_lists(const int* __restrict__ ridx,
                                                   int* __restrict__ counts,
                                                   u32* __restrict__ lists) {
    int n = blockIdx.x * 256 + threadIdx.x;
    if (n >= N_TOK) return;
#pragma unroll
    for (int k = 0; k < 2; ++k) {
        int e = ridx[n * 2 + k];
        int slot = atomicAdd(&counts[e], 1);
        lists[e * N_TOK + slot] = (u32)n | ((u32)k << 16);
    }
}

// ---------------- bf16 MFMA GEMM, C[M,N] = A[M,K] @ B[N,K]^T ----------------
__global__ __launch_bounds__(256) void gemm_bf16_bt(const u16* __restrict__ A,
                                                    const u16* __restrict__ B,
                                                    float* __restrict__ C,
                                                    int M, int N, int K, int out_bf16) {
    __shared__ __align__(16) u16 sA[128 * 64];
    __shared__ __align__(16) u16 sB[128 * 64];
    const int tid = threadIdx.x;
    const int lane = tid & 63;
    const int wave = tid >> 6;
    const int quad = lane >> 4;
    const int l16 = lane & 15;
    const int wm = (wave & 1) * 64;
    const int wn = (wave >> 1) * 64;
    const int bm0 = blockIdx.x * 128;
    const int bn0 = blockIdx.y * 128;

    f32x4 zero = {0.f, 0.f, 0.f, 0.f};
    f32x4 acc[4][4];
#pragma unroll
    for (int i = 0; i < 4; ++i)
#pragma unroll
        for (int j = 0; j < 4; ++j) acc[i][j] = zero;

    for (int k0 = 0; k0 < K; k0 += 64) {
#pragma unroll
        for (int i = 0; i < 4; ++i) {
            int c = i * 256 + tid;
            int r = c >> 3;
            int c8 = (c & 7) << 3;
            const u16* ga = A + (size_t)(bm0 + r) * K + k0 + c8;
            const u16* gb = B + (size_t)(bn0 + r) * K + k0 + c8;
            __builtin_amdgcn_global_load_lds((const __attribute__((address_space(1))) u32*)ga,
                                             (__attribute__((address_space(3))) u32*)(sA + c * 8),
                                             16, 0, 0);
            __builtin_amdgcn_global_load_lds((const __attribute__((address_space(1))) u32*)gb,
                                             (__attribute__((address_space(3))) u32*)(sB + c * 8),
                                             16, 0, 0);
        }
        __syncthreads();
#pragma unroll
        for (int ks = 0; ks < 2; ++ks) {
            bf16x8 af[4], bfv[4];
#pragma unroll
            for (int mi = 0; mi < 4; ++mi)
                af[mi] = *(const bf16x8*)(sA + (wm + mi * 16 + l16) * 64 + ks * 32 + quad * 8);
#pragma unroll
            for (int ni = 0; ni < 4; ++ni)
                bfv[ni] = *(const bf16x8*)(sB + (wn + ni * 16 + l16) * 64 + ks * 32 + quad * 8);
#pragma unroll
            for (int mi = 0; mi < 4; ++mi)
#pragma unroll
                for (int ni = 0; ni < 4; ++ni)
                    acc[mi][ni] = __builtin_amdgcn_mfma_f32_16x16x32_bf16(af[mi], bfv[ni],
                                                                          acc[mi][ni], 0, 0, 0);
        }
        __syncthreads();
    }

#pragma unroll
    for (int mi = 0; mi < 4; ++mi)
#pragma unroll
        for (int ni = 0; ni < 4; ++ni) {
            int col = bn0 + wn + ni * 16 + l16;
#pragma unroll
            for (int i = 0; i < 4; ++i) {
                int row = bm0 + wm + mi * 16 + quad * 4 + i;
                if (out_bf16) {
                    ((u16*)C)[(size_t)row * N + col] = f2bf(acc[mi][ni][i]);
                } else {
                    C[(size_t)row * N + col] = acc[mi][ni][i];
                }
            }
        }
}

// ---------------- expert-grouped activation kernel ----------------
// grid (NT, E, TC), 256 threads. Each lane owns 4 f-columns; all three expert
// weight rows (B1,B3,A2t bf16 [F][16]) live in registers, reused across tokens.
__global__ __launch_bounds__(256, 2) void act_v2(const u16* __restrict__ base1,
                                                 const u16* __restrict__ base3,
                                                 const float* __restrict__ l13,
                                                 const u16* __restrict__ B1b,
                                                 const u16* __restrict__ B3b,
                                                 const u16* __restrict__ A2t,
                                                 const u32* __restrict__ lists,
                                                 const int* __restrict__ counts,
                                                 const float* __restrict__ rw,
                                                 u16* __restrict__ sbuf,
                                                 float* __restrict__ l2part) {
    const int ft = blockIdx.x;
    const int e  = blockIdx.y;
    const int z  = blockIdx.z;
    const int tid = threadIdx.x;
    const int lane = tid & 63;
    const int wave = tid >> 6;
    const int fbase = ft * FT;
    const int f_lane = fbase + lane * 4;

    // stage weights: 4 rows x 16 bf16 per matrix per lane (coalesced 128B/lane)
    u16x8 w1c[8], w3c[8], a2c[8];
    {
        const u16* p1 = B1b + ((size_t)e * F_DIM + f_lane) * 16;
        const u16* p3 = B3b + ((size_t)e * F_DIM + f_lane) * 16;
        const u16* pa = A2t + ((size_t)e * F_DIM + f_lane) * 16;
#pragma unroll
        for (int c = 0; c < 8; ++c) {
            w1c[c] = *(const u16x8*)(p1 + c * 8);
            w3c[c] = *(const u16x8*)(p3 + c * 8);
            a2c[c] = *(const u16x8*)(pa + c * 8);
        }
    }

    const int T = counts[e];
    for (int i = z * 4 + wave; i < T; i += TC * 4) {
        u32 ent = lists[e * N_TOK + i];
        int n = (int)(ent & 0xFFFFu);
        int k = (int)(ent >> 16);
        float wt = rw[n * 2 + k];

        float la1[16], la3[16];
        {
            const float4* pl1 = (const float4*)(l13 + (size_t)n * 256 + e * 16);
            const float4* pl3 = (const float4*)(l13 + (size_t)n * 256 + 128 + e * 16);
#pragma unroll
            for (int q = 0; q < 4; ++q) {
                float4 t1 = pl1[q], t3 = pl3[q];
                la1[q * 4] = LSCALE * t1.x; la1[q * 4 + 1] = LSCALE * t1.y;
                la1[q * 4 + 2] = LSCALE * t1.z; la1[q * 4 + 3] = LSCALE * t1.w;
                la3[q * 4] = LSCALE * t3.x; la3[q * 4 + 1] = LSCALE * t3.y;
                la3[q * 4 + 2] = LSCALE * t3.z; la3[q * 4 + 3] = LSCALE * t3.w;
            }
        }

        ushort4 b1u = *(const ushort4*)(base1 + (size_t)n * F_DIM + f_lane);
        ushort4 b3u = *(const ushort4*)(base3 + (size_t)n * F_DIM + f_lane);
        const u16* b1p = (const u16*)&b1u;
        const u16* b3p = (const u16*)&b3u;

        float l2p[16];
#pragma unroll
        for (int r = 0; r < 16; ++r) l2p[r] = 0.f;
        u16 sv[4];
#pragma unroll
        for (int j = 0; j < 4; ++j) {
            float h1 = bf2f(b1p[j]);
            float h3 = bf2f(b3p[j]);
#pragma unroll
            for (int q = 0; q < 8; ++q) {
                h1 += la1[q] * bf2f(w1c[2 * j][q]);
                h3 += la3[q] * bf2f(w3c[2 * j][q]);
            }
#pragma unroll
            for (int q = 0; q < 8; ++q) {
                h1 += la1[8 + q] * bf2f(w1c[2 * j + 1][q]);
                h3 += la3[8 + q] * bf2f(w3c[2 * j + 1][q]);
            }
            float sg = h1 / (1.f + __expf(-h1));
            float sval = sg * h3;
            sv[j] = f2bf(wt * sval);
#pragma unroll
            for (int q = 0; q < 8; ++q) {
                l2p[q] += sval * bf2f(a2c[2 * j][q]);
                l2p[8 + q] += sval * bf2f(a2c[2 * j + 1][q]);
            }
        }
        *(ushort4*)(sbuf + ((size_t)k * N_TOK + n) * F_DIM + f_lane) = *(ushort4*)sv;

        // wave-reduce 16 l2 partials, lane r<16 writes r-th value
#pragma unroll
        for (int r = 0; r < 16; ++r) {
            float v = l2p[r];
            v += __shfl_xor(v, 1);  v += __shfl_xor(v, 2);
            v += __shfl_xor(v, 4);  v += __shfl_xor(v, 8);
            v += __shfl_xor(v, 16); v += __shfl_xor(v, 32);
            l2p[r] = v;
        }
        float outv = 0.f;
#pragma unroll
        for (int r = 0; r < 16; ++r) outv = (lane == r) ? l2p[r] : outv;
        if (lane < 16)
            l2part[((size_t)(n * 2 + k) * NT + ft) * 16 + lane] = wt * LSCALE * outv;
    }
}

// ---------------- combine: smix = sbuf0 + sbuf1 (weights pre-folded) ----------------
__global__ __launch_bounds__(256) void combine_kernel(const u16* __restrict__ sbuf,
                                                      u16* __restrict__ smix) {
    size_t i = ((size_t)blockIdx.x * 256 + threadIdx.x) * 8;
    u16x8 a = *(const u16x8*)(sbuf + i);
    u16x8 b = *(const u16x8*)(sbuf + (size_t)N_TOK * F_DIM + i);
    u16x8 o;
#pragma unroll
    for (int q = 0; q < 8; ++q) o[q] = f2bf(bf2f(a[q]) + bf2f(b[q]));
    *(u16x8*)(smix + i) = o;
}

// ---------------- LoRA down-projection add: out += (sum of l2 partials) @ B2^T ----------------
__global__ __launch_bounds__(256) void lora_down_v2(const float* __restrict__ l2part,
                                                    const int* __restrict__ ridx,
                                                    const float* __restrict__ B2,
                                                    float* __restrict__ out) {
    int n = blockIdx.x, tid = threadIdx.x;
    __shared__ float c0[16], c1[16];
    __shared__ int se[2];
    if (tid < 2) se[tid] = ridx[n * 2 + tid];
    if (tid < 32) {
        int k = tid >> 4, r = tid & 15;
        const float* p = l2part + ((size_t)(n * 2 + k) * NT) * 16 + r;
        float s = 0.f;
#pragma unroll
        for (int t = 0; t < NT; ++t) s += p[t * 16];
        if (k == 0) c0[r] = s; else c1[r] = s;
    }
    __syncthreads();
    float a0[16], a1v[16];
#pragma unroll
    for (int r = 0; r < 16; ++r) { a0[r] = c0[r]; a1v[r] = c1[r]; }
    const float* B2a = B2 + (size_t)se[0] * D_DIM * R_DIM;
    const float* B2b = B2 + (size_t)se[1] * D_DIM * R_DIM;
    float* orow = out + (size_t)n * D_DIM;
    for (int d = tid; d < D_DIM; d += 256) {
        const float4* pa = (const float4*)(B2a + (size_t)d * 16);
        const float4* pb = (const float4*)(B2b + (size_t)d * 16);
        float acc = 0.f;
#pragma unroll
        for (int q = 0; q < 4; ++q) {
            float4 va = pa[q];
            acc += a0[q * 4] * va.x + a0[q * 4 + 1] * va.y +
                   a0[q * 4 + 2] * va.z + a0[q * 4 + 3] * va.w;
            float4 vb = pb[q];
            acc += a1v[q * 4] * vb.x + a1v[q * 4 + 1] * vb.y +
                   a1v[q * 4 + 2] * vb.z + a1v[q * 4 + 3] * vb.w;
        }
        orow[d] += acc;
    }
}

extern "C" void kernel_launch(void* const* d_in, const int* in_sizes, int n_in,
                              void* d_out, int out_size, void* d_ws, size_t ws_size,
                              hipStream_t stream) {
    const float* x  = (const float*)d_in[0];
    const float* gw = (const float*)d_in[1];
    const float* W1 = (const float*)d_in[2];
    const float* W3 = (const float*)d_in[3];
    const float* W2 = (const float*)d_in[4];
    const float* A1 = (const float*)d_in[5];
    const float* B1 = (const float*)d_in[6];
    const float* A3 = (const float*)d_in[7];
    const float* B3 = (const float*)d_in[8];
    const float* A2 = (const float*)d_in[9];
    const float* B2 = (const float*)d_in[10];
    float* out = (float*)d_out;                          // [N, D]
    float* logits = out + (size_t)N_TOK * D_DIM;         // [N, E]

    char* ws = (char*)d_ws;
    size_t off = 0;
    auto alloc = [&](size_t bytes) { char* p = ws + off; off += (bytes + 255) & ~(size_t)255; return p; };
    u16*   xb    = (u16*)alloc((size_t)N_TOK * D_DIM * 2);
    u16*   W1b   = (u16*)alloc((size_t)F_DIM * D_DIM * 2);
    u16*   W3b   = (u16*)alloc((size_t)F_DIM * D_DIM * 2);
    u16*   W2b   = (u16*)alloc((size_t)D_DIM * F_DIM * 2);
    u16*   A13b  = (u16*)alloc((size_t)256 * D_DIM * 2);
    u16*   base1 = (u16*)alloc((size_t)N_TOK * F_DIM * 2);   // reused as smix later
    u16*   base3 = (u16*)alloc((size_t)N_TOK * F_DIM * 2);
    float* l13   = (float*)alloc((size_t)N_TOK * 256 * 4);
    int*   ridx  = (int*)alloc((size_t)N_TOK * 2 * 4);
    float* rwt   = (float*)alloc((size_t)N_TOK * 2 * 4);
    u16*   B1b   = (u16*)alloc((size_t)E_NUM * F_DIM * R_DIM * 2);
    u16*   B3b   = (u16*)alloc((size_t)E_NUM * F_DIM * R_DIM * 2);
    u16*   A2t   = (u16*)alloc((size_t)E_NUM * F_DIM * R_DIM * 2);
    int*   counts= (int*)alloc(64);
    u32*   lists = (u32*)alloc((size_t)E_NUM * N_TOK * 4);
    u16*   sbuf  = (u16*)alloc((size_t)2 * N_TOK * F_DIM * 2);
    float* l2part= (float*)alloc((size_t)2 * N_TOK * NT * 16 * 4);
    u16*   smixb = base1;  // alias: base1 dead after act_v2
    (void)ws_size; (void)in_sizes; (void)n_in; (void)out_size;

    auto cvt = [&](const float* s, u16* d, size_t cnt) {
        int n4 = (int)(cnt / 4);
        cvt_f32_bf16<<<(n4 + 255) / 256, 256, 0, stream>>>(s, d, n4);
    };
    cvt(x,  xb,  (size_t)N_TOK * D_DIM);
    cvt(W1, W1b, (size_t)F_DIM * D_DIM);
    cvt(W3, W3b, (size_t)F_DIM * D_DIM);
    cvt(W2, W2b, (size_t)D_DIM * F_DIM);
    cvt(A1, A13b, (size_t)128 * D_DIM);
    cvt(A3, A13b + (size_t)128 * D_DIM, (size_t)128 * D_DIM);
    cvt(B1, B1b, (size_t)E_NUM * F_DIM * R_DIM);
    cvt(B3, B3b, (size_t)E_NUM * F_DIM * R_DIM);
    a2_transpose<<<dim3(F_DIM / 256, E_NUM), 256, 0, stream>>>(A2, A2t);

    router_kernel<<<N_TOK, 256, 0, stream>>>(x, gw, logits, ridx, rwt);
    zero_counts<<<1, 64, 0, stream>>>(counts);
    build_lists<<<N_TOK / 256, 256, 0, stream>>>(ridx, counts, lists);

    gemm_bf16_bt<<<dim3(N_TOK / 128, F_DIM / 128), 256, 0, stream>>>(xb, W1b, (float*)base1,
                                                                     N_TOK, F_DIM, D_DIM, 1);
    gemm_bf16_bt<<<dim3(N_TOK / 128, F_DIM / 128), 256, 0, stream>>>(xb, W3b, (float*)base3,
                                                                     N_TOK, F_DIM, D_DIM, 1);
    gemm_bf16_bt<<<dim3(N_TOK / 128, 256 / 128), 256, 0, stream>>>(xb, A13b, l13,
                                                                   N_TOK, 256, D_DIM, 0);

    act_v2<<<dim3(NT, E_NUM, TC), 256, 0, stream>>>(base1, base3, l13, B1b, B3b, A2t,
                                                    lists, counts, rwt, sbuf, l2part);

    combine_kernel<<<(N_TOK * F_DIM / 8) / 256, 256, 0, stream>>>(sbuf, smixb);

    gemm_bf16_bt<<<dim3(N_TOK / 128, D_DIM / 128), 256, 0, stream>>>(smixb, W2b, out,
                                                                     N_TOK, D_DIM, F_DIM, 0);

    lora_down_v2<<<N_TOK, 256, 0, stream>>>(l2part, ridx, B2, out);
}

// Round 3
// 524.908 us; speedup vs baseline: 1.1645x; 1.1645x over previous
//
#include <hip/hip_runtime.h>

typedef unsigned int u32;
typedef unsigned short u16;

#define N_TOK 1024
#define D_DIM 2048
#define F_DIM 5632
#define E_NUM 8
#define R_DIM 16
#define LSCALE 2.0f
#define FT 256            // f-columns per act_v2 block
#define NT (F_DIM / FT)   // 22 F-tiles
#define TC 4              // token chunks per expert
#define BN13 11520        // fused B rows: W1(5632) + W3(5632) + A1(128) + A3(128)

typedef __bf16 bf16x8 __attribute__((ext_vector_type(8)));
typedef float f32x4 __attribute__((ext_vector_type(4)));
typedef u16 u16x8 __attribute__((ext_vector_type(8)));

__device__ inline u16 f2bf(float f) {
    u32 u = __builtin_bit_cast(u32, f);
    u32 r = (u + 0x7fffu + ((u >> 16) & 1u)) >> 16;
    return (u16)r;
}
__device__ inline float bf2f(u16 h) {
    u32 u = ((u32)h) << 16;
    return __builtin_bit_cast(float, u);
}

// ---------------- fp32 -> bf16 conversion (vectorized) ----------------
__global__ __launch_bounds__(256) void cvt_f32_bf16(const float* __restrict__ src,
                                                    u16* __restrict__ dst, int n4) {
    int i = blockIdx.x * 256 + threadIdx.x;
    if (i >= n4) return;
    float4 v = ((const float4*)src)[i];
    union { u16 h[4]; ushort4 u4; } o;
    o.h[0] = f2bf(v.x); o.h[1] = f2bf(v.y); o.h[2] = f2bf(v.z); o.h[3] = f2bf(v.w);
    ((ushort4*)dst)[i] = o.u4;
}

// ---------------- A2 (E,R,F) fp32 -> A2t (E,F,R) bf16 ----------------
__global__ __launch_bounds__(256) void a2_transpose(const float* __restrict__ A2,
                                                    u16* __restrict__ A2t) {
    int e = blockIdx.y;
    int f = blockIdx.x * 256 + threadIdx.x;
    u16 row[16];
#pragma unroll
    for (int r = 0; r < 16; ++r)
        row[r] = f2bf(A2[((size_t)e * R_DIM + r) * F_DIM + f]);
    u16* dst = A2t + ((size_t)e * F_DIM + f) * 16;
#pragma unroll
    for (int q = 0; q < 2; ++q)
        ((ulonglong2*)dst)[q] = ((ulonglong2*)row)[q];
}

// ---------------- router: logits + softmax + top2 ----------------
__global__ __launch_bounds__(256) void router_kernel(const float* __restrict__ x,
                                                     const float* __restrict__ gw,
                                                     float* __restrict__ logits,
                                                     int* __restrict__ ridx,
                                                     float* __restrict__ rw) {
    int n = blockIdx.x;
    int tid = threadIdx.x;
    float part[E_NUM];
#pragma unroll
    for (int e = 0; e < E_NUM; ++e) part[e] = 0.f;
    const float* xr = x + (size_t)n * D_DIM;
    for (int d = tid; d < D_DIM; d += 256) {
        float xv = xr[d];
#pragma unroll
        for (int e = 0; e < E_NUM; ++e) part[e] += xv * gw[e * D_DIM + d];
    }
    __shared__ float sh[E_NUM][256];
#pragma unroll
    for (int e = 0; e < E_NUM; ++e) sh[e][tid] = part[e];
    __syncthreads();
    for (int off = 128; off > 0; off >>= 1) {
        if (tid < off) {
#pragma unroll
            for (int e = 0; e < E_NUM; ++e) sh[e][tid] += sh[e][tid + off];
        }
        __syncthreads();
    }
    if (tid == 0) {
        float lg[E_NUM], p[E_NUM];
        float mx = -1e30f;
        for (int e = 0; e < E_NUM; ++e) {
            lg[e] = sh[e][0];
            logits[n * E_NUM + e] = lg[e];
            if (lg[e] > mx) mx = lg[e];
        }
        float s = 0.f;
        for (int e = 0; e < E_NUM; ++e) { p[e] = expf(lg[e] - mx); s += p[e]; }
        for (int e = 0; e < E_NUM; ++e) p[e] /= s;
        int i1 = 0;
        for (int e = 1; e < E_NUM; ++e) if (p[e] > p[i1]) i1 = e;
        int i2 = (i1 == 0) ? 1 : 0;
        for (int e = 0; e < E_NUM; ++e) if (e != i1 && p[e] > p[i2]) i2 = e;
        float t = p[i1] + p[i2];
        ridx[n * 2] = i1; ridx[n * 2 + 1] = i2;
        rw[n * 2] = p[i1] / t; rw[n * 2 + 1] = p[i2] / t;
    }
}

// ---------------- expert token-list build ----------------
__global__ __launch_bounds__(64) void zero_counts(int* counts) {
    if (threadIdx.x < E_NUM) counts[threadIdx.x] = 0;
}
__global__ __launch_bounds__(256) void build_lists(const int* __restrict__ ridx,
                                                   int* __restrict__ counts,
                                                   u32* __restrict__ lists) {
    int n = blockIdx.x * 256 + threadIdx.x;
    if (n >= N_TOK) return;
#pragma unroll
    for (int k = 0; k < 2; ++k) {
        int e = ridx[n * 2 + k];
        int slot = atomicAdd(&counts[e], 1);
        lists[e * N_TOK + slot] = (u32)n | ((u32)k << 16);
    }
}

// ---------------- bf16 MFMA GEMM, C[M,N] = A[M,K] @ B[N,K]^T ----------------
__global__ __launch_bounds__(256) void gemm_bf16_bt(const u16* __restrict__ A,
                                                    const u16* __restrict__ B,
                                                    float* __restrict__ C,
                                                    int M, int N, int K, int out_bf16) {
    __shared__ __align__(16) u16 sA[128 * 64];
    __shared__ __align__(16) u16 sB[128 * 64];
    const int tid = threadIdx.x;
    const int lane = tid & 63;
    const int wave = tid >> 6;
    const int quad = lane >> 4;
    const int l16 = lane & 15;
    const int wm = (wave & 1) * 64;
    const int wn = (wave >> 1) * 64;
    const int bm0 = blockIdx.x * 128;
    const int bn0 = blockIdx.y * 128;

    f32x4 zero = {0.f, 0.f, 0.f, 0.f};
    f32x4 acc[4][4];
#pragma unroll
    for (int i = 0; i < 4; ++i)
#pragma unroll
        for (int j = 0; j < 4; ++j) acc[i][j] = zero;

    for (int k0 = 0; k0 < K; k0 += 64) {
#pragma unroll
        for (int i = 0; i < 4; ++i) {
            int c = i * 256 + tid;
            int r = c >> 3;
            int c8 = (c & 7) << 3;
            const u16* ga = A + (size_t)(bm0 + r) * K + k0 + c8;
            const u16* gb = B + (size_t)(bn0 + r) * K + k0 + c8;
            __builtin_amdgcn_global_load_lds((const __attribute__((address_space(1))) u32*)ga,
                                             (__attribute__((address_space(3))) u32*)(sA + c * 8),
                                             16, 0, 0);
            __builtin_amdgcn_global_load_lds((const __attribute__((address_space(1))) u32*)gb,
                                             (__attribute__((address_space(3))) u32*)(sB + c * 8),
                                             16, 0, 0);
        }
        __syncthreads();
#pragma unroll
        for (int ks = 0; ks < 2; ++ks) {
            bf16x8 af[4], bfv[4];
#pragma unroll
            for (int mi = 0; mi < 4; ++mi)
                af[mi] = *(const bf16x8*)(sA + (wm + mi * 16 + l16) * 64 + ks * 32 + quad * 8);
#pragma unroll
            for (int ni = 0; ni < 4; ++ni)
                bfv[ni] = *(const bf16x8*)(sB + (wn + ni * 16 + l16) * 64 + ks * 32 + quad * 8);
#pragma unroll
            for (int mi = 0; mi < 4; ++mi)
#pragma unroll
                for (int ni = 0; ni < 4; ++ni)
                    acc[mi][ni] = __builtin_amdgcn_mfma_f32_16x16x32_bf16(af[mi], bfv[ni],
                                                                          acc[mi][ni], 0, 0, 0);
        }
        __syncthreads();
    }

#pragma unroll
    for (int mi = 0; mi < 4; ++mi)
#pragma unroll
        for (int ni = 0; ni < 4; ++ni) {
            int col = bn0 + wn + ni * 16 + l16;
#pragma unroll
            for (int i = 0; i < 4; ++i) {
                int row = bm0 + wm + mi * 16 + quad * 4 + i;
                if (out_bf16) {
                    ((u16*)C)[(size_t)row * N + col] = f2bf(acc[mi][ni][i]);
                } else {
                    C[(size_t)row * N + col] = acc[mi][ni][i];
                }
            }
        }
}

// ---------------- split-K bf16 MFMA GEMM with fp32 atomic-add epilogue ----------------
__global__ __launch_bounds__(256) void gemm_bt_splitk(const u16* __restrict__ A,
                                                      const u16* __restrict__ B,
                                                      float* __restrict__ C,
                                                      int M, int N, int K, int ksplit) {
    __shared__ __align__(16) u16 sA[128 * 64];
    __shared__ __align__(16) u16 sB[128 * 64];
    const int tid = threadIdx.x;
    const int lane = tid & 63;
    const int wave = tid >> 6;
    const int quad = lane >> 4;
    const int l16 = lane & 15;
    const int wm = (wave & 1) * 64;
    const int wn = (wave >> 1) * 64;
    const int bm0 = blockIdx.x * 128;
    const int bn0 = blockIdx.y * 128;
    const int kb = blockIdx.z * ksplit;
    const int ke = kb + ksplit;

    f32x4 zero = {0.f, 0.f, 0.f, 0.f};
    f32x4 acc[4][4];
#pragma unroll
    for (int i = 0; i < 4; ++i)
#pragma unroll
        for (int j = 0; j < 4; ++j) acc[i][j] = zero;

    for (int k0 = kb; k0 < ke; k0 += 64) {
#pragma unroll
        for (int i = 0; i < 4; ++i) {
            int c = i * 256 + tid;
            int r = c >> 3;
            int c8 = (c & 7) << 3;
            const u16* ga = A + (size_t)(bm0 + r) * K + k0 + c8;
            const u16* gb = B + (size_t)(bn0 + r) * K + k0 + c8;
            __builtin_amdgcn_global_load_lds((const __attribute__((address_space(1))) u32*)ga,
                                             (__attribute__((address_space(3))) u32*)(sA + c * 8),
                                             16, 0, 0);
            __builtin_amdgcn_global_load_lds((const __attribute__((address_space(1))) u32*)gb,
                                             (__attribute__((address_space(3))) u32*)(sB + c * 8),
                                             16, 0, 0);
        }
        __syncthreads();
#pragma unroll
        for (int ks = 0; ks < 2; ++ks) {
            bf16x8 af[4], bfv[4];
#pragma unroll
            for (int mi = 0; mi < 4; ++mi)
                af[mi] = *(const bf16x8*)(sA + (wm + mi * 16 + l16) * 64 + ks * 32 + quad * 8);
#pragma unroll
            for (int ni = 0; ni < 4; ++ni)
                bfv[ni] = *(const bf16x8*)(sB + (wn + ni * 16 + l16) * 64 + ks * 32 + quad * 8);
#pragma unroll
            for (int mi = 0; mi < 4; ++mi)
#pragma unroll
                for (int ni = 0; ni < 4; ++ni)
                    acc[mi][ni] = __builtin_amdgcn_mfma_f32_16x16x32_bf16(af[mi], bfv[ni],
                                                                          acc[mi][ni], 0, 0, 0);
        }
        __syncthreads();
    }

#pragma unroll
    for (int mi = 0; mi < 4; ++mi)
#pragma unroll
        for (int ni = 0; ni < 4; ++ni) {
            int col = bn0 + wn + ni * 16 + l16;
#pragma unroll
            for (int i = 0; i < 4; ++i) {
                int row = bm0 + wm + mi * 16 + quad * 4 + i;
                unsafeAtomicAdd(&C[(size_t)row * N + col], acc[mi][ni][i]);
            }
        }
}

// ---------------- expert-grouped activation kernel ----------------
__global__ __launch_bounds__(256, 2) void act_v2(const u16* __restrict__ base13,
                                                 const u16* __restrict__ B1b,
                                                 const u16* __restrict__ B3b,
                                                 const u16* __restrict__ A2t,
                                                 const u32* __restrict__ lists,
                                                 const int* __restrict__ counts,
                                                 const float* __restrict__ rw,
                                                 u16* __restrict__ sbuf,
                                                 float* __restrict__ l2part) {
    const int ft = blockIdx.x;
    const int e  = blockIdx.y;
    const int z  = blockIdx.z;
    const int tid = threadIdx.x;
    const int lane = tid & 63;
    const int wave = tid >> 6;
    const int fbase = ft * FT;
    const int f_lane = fbase + lane * 4;

    // stage weights: 4 rows x 16 bf16 per matrix per lane
    u16x8 w1c[8], w3c[8], a2c[8];
    {
        const u16* p1 = B1b + ((size_t)e * F_DIM + f_lane) * 16;
        const u16* p3 = B3b + ((size_t)e * F_DIM + f_lane) * 16;
        const u16* pa = A2t + ((size_t)e * F_DIM + f_lane) * 16;
#pragma unroll
        for (int c = 0; c < 8; ++c) {
            w1c[c] = *(const u16x8*)(p1 + c * 8);
            w3c[c] = *(const u16x8*)(p3 + c * 8);
            a2c[c] = *(const u16x8*)(pa + c * 8);
        }
    }

    const int T = counts[e];
    for (int i = z * 4 + wave; i < T; i += TC * 4) {
        u32 ent = lists[e * N_TOK + i];
        int n = (int)(ent & 0xFFFFu);
        int k = (int)(ent >> 16);
        float wt = rw[n * 2 + k];

        float la1[16], la3[16];
        {
            const u16x8* pl1 = (const u16x8*)(base13 + (size_t)n * BN13 + 11264 + e * 16);
            const u16x8* pl3 = (const u16x8*)(base13 + (size_t)n * BN13 + 11392 + e * 16);
#pragma unroll
            for (int h = 0; h < 2; ++h) {
                u16x8 t1 = pl1[h], t3 = pl3[h];
#pragma unroll
                for (int q = 0; q < 8; ++q) {
                    la1[h * 8 + q] = LSCALE * bf2f(t1[q]);
                    la3[h * 8 + q] = LSCALE * bf2f(t3[q]);
                }
            }
        }

        ushort4 b1u = *(const ushort4*)(base13 + (size_t)n * BN13 + f_lane);
        ushort4 b3u = *(const ushort4*)(base13 + (size_t)n * BN13 + 5632 + f_lane);
        const u16* b1p = (const u16*)&b1u;
        const u16* b3p = (const u16*)&b3u;

        float l2p[16];
#pragma unroll
        for (int r = 0; r < 16; ++r) l2p[r] = 0.f;
        u16 sv[4];
#pragma unroll
        for (int j = 0; j < 4; ++j) {
            float h1 = bf2f(b1p[j]);
            float h3 = bf2f(b3p[j]);
#pragma unroll
            for (int q = 0; q < 8; ++q) {
                h1 += la1[q] * bf2f(w1c[2 * j][q]);
                h3 += la3[q] * bf2f(w3c[2 * j][q]);
            }
#pragma unroll
            for (int q = 0; q < 8; ++q) {
                h1 += la1[8 + q] * bf2f(w1c[2 * j + 1][q]);
                h3 += la3[8 + q] * bf2f(w3c[2 * j + 1][q]);
            }
            float sg = h1 / (1.f + __expf(-h1));
            float sval = sg * h3;
            sv[j] = f2bf(wt * sval);
#pragma unroll
            for (int q = 0; q < 8; ++q) {
                l2p[q] += sval * bf2f(a2c[2 * j][q]);
                l2p[8 + q] += sval * bf2f(a2c[2 * j + 1][q]);
            }
        }
        *(ushort4*)(sbuf + ((size_t)k * N_TOK + n) * F_DIM + f_lane) = *(ushort4*)sv;

#pragma unroll
        for (int r = 0; r < 16; ++r) {
            float v = l2p[r];
            v += __shfl_xor(v, 1);  v += __shfl_xor(v, 2);
            v += __shfl_xor(v, 4);  v += __shfl_xor(v, 8);
            v += __shfl_xor(v, 16); v += __shfl_xor(v, 32);
            l2p[r] = v;
        }
        float outv = 0.f;
#pragma unroll
        for (int r = 0; r < 16; ++r) outv = (lane == r) ? l2p[r] : outv;
        if (lane < 16)
            l2part[((size_t)(n * 2 + k) * NT + ft) * 16 + lane] = wt * LSCALE * outv;
    }
}

// ---------------- combine: smix = sbuf0 + sbuf1 ----------------
__global__ __launch_bounds__(256) void combine_kernel(const u16* __restrict__ sbuf,
                                                      u16* __restrict__ smix) {
    size_t i = ((size_t)blockIdx.x * 256 + threadIdx.x) * 8;
    u16x8 a = *(const u16x8*)(sbuf + i);
    u16x8 b = *(const u16x8*)(sbuf + (size_t)N_TOK * F_DIM + i);
    u16x8 o;
#pragma unroll
    for (int q = 0; q < 8; ++q) o[q] = f2bf(bf2f(a[q]) + bf2f(b[q]));
    *(u16x8*)(smix + i) = o;
}

// ---------------- LoRA down-projection (WRITES out, runs before split-K GEMM) ----------------
__global__ __launch_bounds__(256) void lora_down_v2(const float* __restrict__ l2part,
                                                    const int* __restrict__ ridx,
                                                    const float* __restrict__ B2,
                                                    float* __restrict__ out) {
    int n = blockIdx.x, tid = threadIdx.x;
    __shared__ float c0[16], c1[16];
    __shared__ int se[2];
    if (tid < 2) se[tid] = ridx[n * 2 + tid];
    if (tid < 32) {
        int k = tid >> 4, r = tid & 15;
        const float* p = l2part + ((size_t)(n * 2 + k) * NT) * 16 + r;
        float s = 0.f;
#pragma unroll
        for (int t = 0; t < NT; ++t) s += p[t * 16];
        if (k == 0) c0[r] = s; else c1[r] = s;
    }
    __syncthreads();
    float a0[16], a1v[16];
#pragma unroll
    for (int r = 0; r < 16; ++r) { a0[r] = c0[r]; a1v[r] = c1[r]; }
    const float* B2a = B2 + (size_t)se[0] * D_DIM * R_DIM;
    const float* B2b = B2 + (size_t)se[1] * D_DIM * R_DIM;
    float* orow = out + (size_t)n * D_DIM;
    for (int d = tid; d < D_DIM; d += 256) {
        const float4* pa = (const float4*)(B2a + (size_t)d * 16);
        const float4* pb = (const float4*)(B2b + (size_t)d * 16);
        float acc = 0.f;
#pragma unroll
        for (int q = 0; q < 4; ++q) {
            float4 va = pa[q];
            acc += a0[q * 4] * va.x + a0[q * 4 + 1] * va.y +
                   a0[q * 4 + 2] * va.z + a0[q * 4 + 3] * va.w;
            float4 vb = pb[q];
            acc += a1v[q * 4] * vb.x + a1v[q * 4 + 1] * vb.y +
                   a1v[q * 4 + 2] * vb.z + a1v[q * 4 + 3] * vb.w;
        }
        orow[d] = acc;  // WRITE (initializes out for the atomic GEMM)
    }
}

extern "C" void kernel_launch(void* const* d_in, const int* in_sizes, int n_in,
                              void* d_out, int out_size, void* d_ws, size_t ws_size,
                              hipStream_t stream) {
    const float* x  = (const float*)d_in[0];
    const float* gw = (const float*)d_in[1];
    const float* W1 = (const float*)d_in[2];
    const float* W3 = (const float*)d_in[3];
    const float* W2 = (const float*)d_in[4];
    const float* A1 = (const float*)d_in[5];
    const float* B1 = (const float*)d_in[6];
    const float* A3 = (const float*)d_in[7];
    const float* B3 = (const float*)d_in[8];
    const float* A2 = (const float*)d_in[9];
    const float* B2 = (const float*)d_in[10];
    float* out = (float*)d_out;                          // [N, D]
    float* logits = out + (size_t)N_TOK * D_DIM;         // [N, E]

    char* ws = (char*)d_ws;
    size_t off = 0;
    auto alloc = [&](size_t bytes) { char* p = ws + off; off += (bytes + 255) & ~(size_t)255; return p; };
    u16*   xb    = (u16*)alloc((size_t)N_TOK * D_DIM * 2);
    u16*   W13b  = (u16*)alloc((size_t)BN13 * D_DIM * 2);     // W1 | W3 | A1 | A3
    u16*   W2b   = (u16*)alloc((size_t)D_DIM * F_DIM * 2);
    u16*   base13= (u16*)alloc((size_t)N_TOK * BN13 * 2);     // base1 | base3 | l13 (bf16)
    int*   ridx  = (int*)alloc((size_t)N_TOK * 2 * 4);
    float* rwt   = (float*)alloc((size_t)N_TOK * 2 * 4);
    u16*   B1b   = (u16*)alloc((size_t)E_NUM * F_DIM * R_DIM * 2);
    u16*   B3b   = (u16*)alloc((size_t)E_NUM * F_DIM * R_DIM * 2);
    u16*   A2t   = (u16*)alloc((size_t)E_NUM * F_DIM * R_DIM * 2);
    int*   counts= (int*)alloc(64);
    u32*   lists = (u32*)alloc((size_t)E_NUM * N_TOK * 4);
    u16*   sbuf  = (u16*)alloc((size_t)2 * N_TOK * F_DIM * 2);
    float* l2part= (float*)alloc((size_t)2 * N_TOK * NT * 16 * 4);
    u16*   smixb = (u16*)alloc((size_t)N_TOK * F_DIM * 2);
    (void)ws_size; (void)in_sizes; (void)n_in; (void)out_size;

    auto cvt = [&](const float* s, u16* d, size_t cnt) {
        int n4 = (int)(cnt / 4);
        cvt_f32_bf16<<<(n4 + 255) / 256, 256, 0, stream>>>(s, d, n4);
    };
    cvt(x,  xb,  (size_t)N_TOK * D_DIM);
    cvt(W1, W13b, (size_t)F_DIM * D_DIM);
    cvt(W3, W13b + (size_t)F_DIM * D_DIM, (size_t)F_DIM * D_DIM);
    cvt(A1, W13b + (size_t)2 * F_DIM * D_DIM, (size_t)128 * D_DIM);
    cvt(A3, W13b + (size_t)2 * F_DIM * D_DIM + (size_t)128 * D_DIM, (size_t)128 * D_DIM);
    cvt(W2, W2b, (size_t)D_DIM * F_DIM);
    cvt(B1, B1b, (size_t)E_NUM * F_DIM * R_DIM);
    cvt(B3, B3b, (size_t)E_NUM * F_DIM * R_DIM);
    a2_transpose<<<dim3(F_DIM / 256, E_NUM), 256, 0, stream>>>(A2, A2t);

    router_kernel<<<N_TOK, 256, 0, stream>>>(x, gw, logits, ridx, rwt);
    zero_counts<<<1, 64, 0, stream>>>(counts);
    build_lists<<<N_TOK / 256, 256, 0, stream>>>(ridx, counts, lists);

    // one fused GEMM: [base1 | base3 | l13] = x @ [W1;W3;A1;A3]^T   (720 blocks)
    gemm_bf16_bt<<<dim3(N_TOK / 128, BN13 / 128), 256, 0, stream>>>(xb, W13b, (float*)base13,
                                                                    N_TOK, BN13, D_DIM, 1);

    act_v2<<<dim3(NT, E_NUM, TC), 256, 0, stream>>>(base13, B1b, B3b, A2t,
                                                    lists, counts, rwt, sbuf, l2part);

    combine_kernel<<<(N_TOK * F_DIM / 8) / 256, 256, 0, stream>>>(sbuf, smixb);

    // initialize out with the LoRA-down contribution, then split-K GEMM atomically adds
    lora_down_v2<<<N_TOK, 256, 0, stream>>>(l2part, ridx, B2, out);

    gemm_bt_splitk<<<dim3(N_TOK / 128, D_DIM / 128, 4), 256, 0, stream>>>(smixb, W2b, out,
                                                                          N_TOK, D_DIM, F_DIM,
                                                                          F_DIM / 4);
}

// Round 5
// 466.015 us; speedup vs baseline: 1.3117x; 1.1264x over previous
//
#include <hip/hip_runtime.h>

typedef unsigned int u32;
typedef unsigned short u16;

#define N_TOK 1024
#define D_DIM 2048
#define F_DIM 5632
#define E_NUM 8
#define R_DIM 16
#define LSCALE 2.0f
#define FT 256            // f-columns per act block
#define NT (F_DIM / FT)   // 22 F-tiles
#define TC 8              // token chunks per expert
#define BN13 11520        // fused B rows: W1(5632) + W3(5632) + A1(128) + A3(128)

typedef __bf16 bf16x8 __attribute__((ext_vector_type(8)));
typedef float f32x4 __attribute__((ext_vector_type(4)));
typedef u16 u16x8 __attribute__((ext_vector_type(8)));

__device__ inline u16 f2bf(float f) {
    u32 u = __builtin_bit_cast(u32, f);
    u32 r = (u + 0x7fffu + ((u >> 16) & 1u)) >> 16;
    return (u16)r;
}
__device__ inline float bf2f(u16 h) {
    u32 u = ((u32)h) << 16;
    return __builtin_bit_cast(float, u);
}

// ---------------- fp32 -> bf16 conversion (vectorized) ----------------
__global__ __launch_bounds__(256) void cvt_f32_bf16(const float* __restrict__ src,
                                                    u16* __restrict__ dst, int n4) {
    int i = blockIdx.x * 256 + threadIdx.x;
    if (i >= n4) return;
    float4 v = ((const float4*)src)[i];
    union { u16 h[4]; ushort4 u4; } o;
    o.h[0] = f2bf(v.x); o.h[1] = f2bf(v.y); o.h[2] = f2bf(v.z); o.h[3] = f2bf(v.w);
    ((ushort4*)dst)[i] = o.u4;
}

// ---------------- A2 (E,R,F) fp32 -> A2t (E,F,R) bf16 ----------------
__global__ __launch_bounds__(256) void a2_transpose(const float* __restrict__ A2,
                                                    u16* __restrict__ A2t) {
    int e = blockIdx.y;
    int f = blockIdx.x * 256 + threadIdx.x;
    u16 row[16];
#pragma unroll
    for (int r = 0; r < 16; ++r)
        row[r] = f2bf(A2[((size_t)e * R_DIM + r) * F_DIM + f]);
    u16* dst = A2t + ((size_t)e * F_DIM + f) * 16;
#pragma unroll
    for (int q = 0; q < 2; ++q)
        ((ulonglong2*)dst)[q] = ((ulonglong2*)row)[q];
}

// ---------------- router: logits + softmax + top2 ----------------
__global__ __launch_bounds__(256) void router_kernel(const float* __restrict__ x,
                                                     const float* __restrict__ gw,
                                                     float* __restrict__ logits,
                                                     int* __restrict__ ridx,
                                                     float* __restrict__ rw) {
    int n = blockIdx.x;
    int tid = threadIdx.x;
    float part[E_NUM];
#pragma unroll
    for (int e = 0; e < E_NUM; ++e) part[e] = 0.f;
    const float* xr = x + (size_t)n * D_DIM;
    for (int d = tid; d < D_DIM; d += 256) {
        float xv = xr[d];
#pragma unroll
        for (int e = 0; e < E_NUM; ++e) part[e] += xv * gw[e * D_DIM + d];
    }
    __shared__ float sh[E_NUM][256];
#pragma unroll
    for (int e = 0; e < E_NUM; ++e) sh[e][tid] = part[e];
    __syncthreads();
    for (int off = 128; off > 0; off >>= 1) {
        if (tid < off) {
#pragma unroll
            for (int e = 0; e < E_NUM; ++e) sh[e][tid] += sh[e][tid + off];
        }
        __syncthreads();
    }
    if (tid == 0) {
        float lg[E_NUM], p[E_NUM];
        float mx = -1e30f;
        for (int e = 0; e < E_NUM; ++e) {
            lg[e] = sh[e][0];
            logits[n * E_NUM + e] = lg[e];
            if (lg[e] > mx) mx = lg[e];
        }
        float s = 0.f;
        for (int e = 0; e < E_NUM; ++e) { p[e] = expf(lg[e] - mx); s += p[e]; }
        for (int e = 0; e < E_NUM; ++e) p[e] /= s;
        int i1 = 0;
        for (int e = 1; e < E_NUM; ++e) if (p[e] > p[i1]) i1 = e;
        int i2 = (i1 == 0) ? 1 : 0;
        for (int e = 0; e < E_NUM; ++e) if (e != i1 && p[e] > p[i2]) i2 = e;
        float t = p[i1] + p[i2];
        ridx[n * 2] = i1; ridx[n * 2 + 1] = i2;
        rw[n * 2] = p[i1] / t; rw[n * 2 + 1] = p[i2] / t;
    }
}

// ---------------- expert token-list build ----------------
__global__ __launch_bounds__(64) void zero_counts(int* counts) {
    if (threadIdx.x < E_NUM) counts[threadIdx.x] = 0;
}
__global__ __launch_bounds__(256) void build_lists(const int* __restrict__ ridx,
                                                   int* __restrict__ counts,
                                                   u32* __restrict__ lists) {
    int n = blockIdx.x * 256 + threadIdx.x;
    if (n >= N_TOK) return;
#pragma unroll
    for (int k = 0; k < 2; ++k) {
        int e = ridx[n * 2 + k];
        int slot = atomicAdd(&counts[e], 1);
        lists[e * N_TOK + slot] = (u32)n | ((u32)k << 16);
    }
}

// ---------------- bf16 MFMA GEMM, C[M,N] = A[M,K] @ B[N,K]^T ----------------
__global__ __launch_bounds__(256) void gemm_bf16_bt(const u16* __restrict__ A,
                                                    const u16* __restrict__ B,
                                                    float* __restrict__ C,
                                                    int M, int N, int K, int out_bf16) {
    __shared__ __align__(16) u16 sA[128 * 64];
    __shared__ __align__(16) u16 sB[128 * 64];
    const int tid = threadIdx.x;
    const int lane = tid & 63;
    const int wave = tid >> 6;
    const int quad = lane >> 4;
    const int l16 = lane & 15;
    const int wm = (wave & 1) * 64;
    const int wn = (wave >> 1) * 64;
    const int bm0 = blockIdx.x * 128;
    const int bn0 = blockIdx.y * 128;

    f32x4 zero = {0.f, 0.f, 0.f, 0.f};
    f32x4 acc[4][4];
#pragma unroll
    for (int i = 0; i < 4; ++i)
#pragma unroll
        for (int j = 0; j < 4; ++j) acc[i][j] = zero;

    for (int k0 = 0; k0 < K; k0 += 64) {
#pragma unroll
        for (int i = 0; i < 4; ++i) {
            int c = i * 256 + tid;
            int r = c >> 3;
            int c8 = (c & 7) << 3;
            const u16* ga = A + (size_t)(bm0 + r) * K + k0 + c8;
            const u16* gb = B + (size_t)(bn0 + r) * K + k0 + c8;
            __builtin_amdgcn_global_load_lds((const __attribute__((address_space(1))) u32*)ga,
                                             (__attribute__((address_space(3))) u32*)(sA + c * 8),
                                             16, 0, 0);
            __builtin_amdgcn_global_load_lds((const __attribute__((address_space(1))) u32*)gb,
                                             (__attribute__((address_space(3))) u32*)(sB + c * 8),
                                             16, 0, 0);
        }
        __syncthreads();
#pragma unroll
        for (int ks = 0; ks < 2; ++ks) {
            bf16x8 af[4], bfv[4];
#pragma unroll
            for (int mi = 0; mi < 4; ++mi)
                af[mi] = *(const bf16x8*)(sA + (wm + mi * 16 + l16) * 64 + ks * 32 + quad * 8);
#pragma unroll
            for (int ni = 0; ni < 4; ++ni)
                bfv[ni] = *(const bf16x8*)(sB + (wn + ni * 16 + l16) * 64 + ks * 32 + quad * 8);
#pragma unroll
            for (int mi = 0; mi < 4; ++mi)
#pragma unroll
                for (int ni = 0; ni < 4; ++ni)
                    acc[mi][ni] = __builtin_amdgcn_mfma_f32_16x16x32_bf16(af[mi], bfv[ni],
                                                                          acc[mi][ni], 0, 0, 0);
        }
        __syncthreads();
    }

#pragma unroll
    for (int mi = 0; mi < 4; ++mi)
#pragma unroll
        for (int ni = 0; ni < 4; ++ni) {
            int col = bn0 + wn + ni * 16 + l16;
#pragma unroll
            for (int i = 0; i < 4; ++i) {
                int row = bm0 + wm + mi * 16 + quad * 4 + i;
                if (out_bf16) {
                    ((u16*)C)[(size_t)row * N + col] = f2bf(acc[mi][ni][i]);
                } else {
                    C[(size_t)row * N + col] = acc[mi][ni][i];
                }
            }
        }
}

// ---------------- split-K bf16 MFMA GEMM with fp32 atomic-add epilogue ----------------
__global__ __launch_bounds__(256) void gemm_bt_splitk(const u16* __restrict__ A,
                                                      const u16* __restrict__ B,
                                                      float* __restrict__ C,
                                                      int M, int N, int K, int ksplit) {
    __shared__ __align__(16) u16 sA[128 * 64];
    __shared__ __align__(16) u16 sB[128 * 64];
    const int tid = threadIdx.x;
    const int lane = tid & 63;
    const int wave = tid >> 6;
    const int quad = lane >> 4;
    const int l16 = lane & 15;
    const int wm = (wave & 1) * 64;
    const int wn = (wave >> 1) * 64;
    const int bm0 = blockIdx.x * 128;
    const int bn0 = blockIdx.y * 128;
    const int kb = blockIdx.z * ksplit;
    const int ke = kb + ksplit;

    f32x4 zero = {0.f, 0.f, 0.f, 0.f};
    f32x4 acc[4][4];
#pragma unroll
    for (int i = 0; i < 4; ++i)
#pragma unroll
        for (int j = 0; j < 4; ++j) acc[i][j] = zero;

    for (int k0 = kb; k0 < ke; k0 += 64) {
#pragma unroll
        for (int i = 0; i < 4; ++i) {
            int c = i * 256 + tid;
            int r = c >> 3;
            int c8 = (c & 7) << 3;
            const u16* ga = A + (size_t)(bm0 + r) * K + k0 + c8;
            const u16* gb = B + (size_t)(bn0 + r) * K + k0 + c8;
            __builtin_amdgcn_global_load_lds((const __attribute__((address_space(1))) u32*)ga,
                                             (__attribute__((address_space(3))) u32*)(sA + c * 8),
                                             16, 0, 0);
            __builtin_amdgcn_global_load_lds((const __attribute__((address_space(1))) u32*)gb,
                                             (__attribute__((address_space(3))) u32*)(sB + c * 8),
                                             16, 0, 0);
        }
        __syncthreads();
#pragma unroll
        for (int ks = 0; ks < 2; ++ks) {
            bf16x8 af[4], bfv[4];
#pragma unroll
            for (int mi = 0; mi < 4; ++mi)
                af[mi] = *(const bf16x8*)(sA + (wm + mi * 16 + l16) * 64 + ks * 32 + quad * 8);
#pragma unroll
            for (int ni = 0; ni < 4; ++ni)
                bfv[ni] = *(const bf16x8*)(sB + (wn + ni * 16 + l16) * 64 + ks * 32 + quad * 8);
#pragma unroll
            for (int mi = 0; mi < 4; ++mi)
#pragma unroll
                for (int ni = 0; ni < 4; ++ni)
                    acc[mi][ni] = __builtin_amdgcn_mfma_f32_16x16x32_bf16(af[mi], bfv[ni],
                                                                          acc[mi][ni], 0, 0, 0);
        }
        __syncthreads();
    }

#pragma unroll
    for (int mi = 0; mi < 4; ++mi)
#pragma unroll
        for (int ni = 0; ni < 4; ++ni) {
            int col = bn0 + wn + ni * 16 + l16;
#pragma unroll
            for (int i = 0; i < 4; ++i) {
                int row = bm0 + wm + mi * 16 + quad * 4 + i;
                unsafeAtomicAdd(&C[(size_t)row * N + col], acc[mi][ni][i]);
            }
        }
}

// ---------------- expert-grouped activation kernel (R2-proven bf16 math, no l2) ----------------
// grid (NT, E, TC), 256 threads. Each lane owns 4 f-columns; B1/B3 expert rows
// live in registers, reused across tokens. l2 is NOT computed here (lora_down_v3
// recomputes it from sbuf).
__global__ __launch_bounds__(256) void act_v2b(const u16* __restrict__ base13,
                                               const u16* __restrict__ B1b,
                                               const u16* __restrict__ B3b,
                                               const u32* __restrict__ lists,
                                               const int* __restrict__ counts,
                                               const float* __restrict__ rw,
                                               u16* __restrict__ sbuf) {
    const int ft = blockIdx.x;
    const int e  = blockIdx.y;
    const int z  = blockIdx.z;
    const int tid = threadIdx.x;
    const int lane = tid & 63;
    const int wave = tid >> 6;
    const int f_lane = ft * FT + lane * 4;

    // stage weights: 4 f-cols x 16 r bf16 per matrix per lane
    u16x8 w1c[8], w3c[8];
    {
        const u16* p1 = B1b + ((size_t)e * F_DIM + f_lane) * 16;
        const u16* p3 = B3b + ((size_t)e * F_DIM + f_lane) * 16;
#pragma unroll
        for (int c = 0; c < 8; ++c) {
            w1c[c] = *(const u16x8*)(p1 + c * 8);
            w3c[c] = *(const u16x8*)(p3 + c * 8);
        }
    }

    const int T = counts[e];
    for (int i = z * 4 + wave; i < T; i += TC * 4) {
        u32 ent = lists[e * N_TOK + i];
        int n = (int)(ent & 0xFFFFu);
        int k = (int)(ent >> 16);
        float wt = rw[n * 2 + k];

        float la1[16], la3[16];
        {
            const u16x8* pl1 = (const u16x8*)(base13 + (size_t)n * BN13 + 11264 + e * 16);
            const u16x8* pl3 = (const u16x8*)(base13 + (size_t)n * BN13 + 11392 + e * 16);
#pragma unroll
            for (int h = 0; h < 2; ++h) {
                u16x8 t1 = pl1[h], t3 = pl3[h];
#pragma unroll
                for (int q = 0; q < 8; ++q) {
                    la1[h * 8 + q] = LSCALE * bf2f(t1[q]);
                    la3[h * 8 + q] = LSCALE * bf2f(t3[q]);
                }
            }
        }

        ushort4 b1u = *(const ushort4*)(base13 + (size_t)n * BN13 + f_lane);
        ushort4 b3u = *(const ushort4*)(base13 + (size_t)n * BN13 + 5632 + f_lane);
        const u16* b1p = (const u16*)&b1u;
        const u16* b3p = (const u16*)&b3u;

        u16 sv[4];
#pragma unroll
        for (int j = 0; j < 4; ++j) {
            float h1 = bf2f(b1p[j]);
            float h3 = bf2f(b3p[j]);
#pragma unroll
            for (int q = 0; q < 8; ++q) {
                h1 += la1[q] * bf2f(w1c[2 * j][q]);
                h3 += la3[q] * bf2f(w3c[2 * j][q]);
            }
#pragma unroll
            for (int q = 0; q < 8; ++q) {
                h1 += la1[8 + q] * bf2f(w1c[2 * j + 1][q]);
                h3 += la3[8 + q] * bf2f(w3c[2 * j + 1][q]);
            }
            float sg = h1 / (1.f + __expf(-h1));
            sv[j] = f2bf(wt * sg * h3);
        }
        *(ushort4*)(sbuf + ((size_t)k * N_TOK + n) * F_DIM + f_lane) = *(ushort4*)sv;
    }
}

// ---------------- combine: smix = sbuf0 + sbuf1 (bf16, weights pre-folded) ----------------
__global__ __launch_bounds__(256) void combine_kernel(const u16* __restrict__ sbuf,
                                                      u16* __restrict__ smix) {
    size_t i = ((size_t)blockIdx.x * 256 + threadIdx.x) * 8;
    u16x8 a = *(const u16x8*)(sbuf + i);
    u16x8 b = *(const u16x8*)(sbuf + (size_t)N_TOK * F_DIM + i);
    u16x8 o;
#pragma unroll
    for (int q = 0; q < 8; ++q) o[q] = f2bf(bf2f(a[q]) + bf2f(b[q]));
    *(u16x8*)(smix + i) = o;
}

// ---------------- lora_down_v3: l2 = LSCALE*(sbuf @ A2t), out = l2 @ B2^T (WRITES out) ----------------
// one block per token; sbuf bf16 carries wt*sval; A2t bf16 unscaled.
__global__ __launch_bounds__(256) void lora_down_v3(const u16* __restrict__ sbuf,
                                                    const u16* __restrict__ A2t,
                                                    const int* __restrict__ ridx,
                                                    const float* __restrict__ B2,
                                                    float* __restrict__ out) {
    const int n = blockIdx.x, tid = threadIdx.x;
    __shared__ float part[2][32][16];
    __shared__ float fin[2][16];
    __shared__ int se[2];
    if (tid < 2) se[tid] = ridx[n * 2 + tid];
    __syncthreads();

    {
        const int k = tid >> 7;          // 0 or 1
        const int tt = tid & 127;
        const int rq = tt & 3;           // r-group of 4
        const int fc = tt >> 2;          // 32 f-chunks of 176
        const int e = se[k];
        const u16* srow = sbuf + ((size_t)k * N_TOK + n) * F_DIM + fc * 176;
        const u16* arow = A2t + ((size_t)e * F_DIM + fc * 176) * 16 + rq * 4;
        float acc0 = 0.f, acc1 = 0.f, acc2 = 0.f, acc3 = 0.f;
#pragma unroll 4
        for (int f = 0; f < 176; ++f) {
            float sv = bf2f(srow[f]);
            ushort4 wr = *(const ushort4*)(arow + (size_t)f * 16);
            acc0 += sv * bf2f(wr.x);
            acc1 += sv * bf2f(wr.y);
            acc2 += sv * bf2f(wr.z);
            acc3 += sv * bf2f(wr.w);
        }
        part[k][fc][rq * 4 + 0] = acc0;
        part[k][fc][rq * 4 + 1] = acc1;
        part[k][fc][rq * 4 + 2] = acc2;
        part[k][fc][rq * 4 + 3] = acc3;
    }
    __syncthreads();
    if (tid < 32) {
        int k = tid >> 4, r = tid & 15;
        float s = 0.f;
#pragma unroll
        for (int fc = 0; fc < 32; ++fc) s += part[k][fc][r];
        fin[k][r] = LSCALE * s;
    }
    __syncthreads();

    float a0[16], a1v[16];
#pragma unroll
    for (int r = 0; r < 16; ++r) { a0[r] = fin[0][r]; a1v[r] = fin[1][r]; }
    const float* B2a = B2 + (size_t)se[0] * D_DIM * R_DIM;
    const float* B2b = B2 + (size_t)se[1] * D_DIM * R_DIM;
    float* orow = out + (size_t)n * D_DIM;
    for (int d = tid; d < D_DIM; d += 256) {
        const float4* pa = (const float4*)(B2a + (size_t)d * 16);
        const float4* pb = (const float4*)(B2b + (size_t)d * 16);
        float acc = 0.f;
#pragma unroll
        for (int q = 0; q < 4; ++q) {
            float4 va = pa[q];
            acc += a0[q * 4] * va.x + a0[q * 4 + 1] * va.y +
                   a0[q * 4 + 2] * va.z + a0[q * 4 + 3] * va.w;
            float4 vb = pb[q];
            acc += a1v[q * 4] * vb.x + a1v[q * 4 + 1] * vb.y +
                   a1v[q * 4 + 2] * vb.z + a1v[q * 4 + 3] * vb.w;
        }
        orow[d] = acc;  // WRITE (initializes out for the atomic split-K GEMM)
    }
}

extern "C" void kernel_launch(void* const* d_in, const int* in_sizes, int n_in,
                              void* d_out, int out_size, void* d_ws, size_t ws_size,
                              hipStream_t stream) {
    const float* x  = (const float*)d_in[0];
    const float* gw = (const float*)d_in[1];
    const float* W1 = (const float*)d_in[2];
    const float* W3 = (const float*)d_in[3];
    const float* W2 = (const float*)d_in[4];
    const float* A1 = (const float*)d_in[5];
    const float* B1 = (const float*)d_in[6];
    const float* A3 = (const float*)d_in[7];
    const float* B3 = (const float*)d_in[8];
    const float* A2 = (const float*)d_in[9];
    const float* B2 = (const float*)d_in[10];
    float* out = (float*)d_out;                          // [N, D]
    float* logits = out + (size_t)N_TOK * D_DIM;         // [N, E]

    char* ws = (char*)d_ws;
    size_t off = 0;
    auto alloc = [&](size_t bytes) { char* p = ws + off; off += (bytes + 255) & ~(size_t)255; return p; };
    u16*   xb    = (u16*)alloc((size_t)N_TOK * D_DIM * 2);
    u16*   W13b  = (u16*)alloc((size_t)BN13 * D_DIM * 2);     // W1 | W3 | A1 | A3 (bf16)
    u16*   W2b   = (u16*)alloc((size_t)D_DIM * F_DIM * 2);
    u16*   base13= (u16*)alloc((size_t)N_TOK * BN13 * 2);     // bf16: base1 | base3 | l13
    int*   ridx  = (int*)alloc((size_t)N_TOK * 2 * 4);
    float* rwt   = (float*)alloc((size_t)N_TOK * 2 * 4);
    u16*   B1b   = (u16*)alloc((size_t)E_NUM * F_DIM * R_DIM * 2);  // bf16
    u16*   B3b   = (u16*)alloc((size_t)E_NUM * F_DIM * R_DIM * 2);  // bf16
    u16*   A2t   = (u16*)alloc((size_t)E_NUM * F_DIM * R_DIM * 2);  // bf16
    int*   counts= (int*)alloc(64);
    u32*   lists = (u32*)alloc((size_t)E_NUM * N_TOK * 4);
    u16*   sbuf  = (u16*)alloc((size_t)2 * N_TOK * F_DIM * 2);      // bf16
    u16*   smixb = (u16*)alloc((size_t)N_TOK * F_DIM * 2);          // bf16
    (void)ws_size; (void)in_sizes; (void)n_in; (void)out_size;

    auto cvt = [&](const float* s, u16* d, size_t cnt) {
        int n4 = (int)(cnt / 4);
        cvt_f32_bf16<<<(n4 + 255) / 256, 256, 0, stream>>>(s, d, n4);
    };
    cvt(x,  xb,  (size_t)N_TOK * D_DIM);
    cvt(W1, W13b, (size_t)F_DIM * D_DIM);
    cvt(W3, W13b + (size_t)F_DIM * D_DIM, (size_t)F_DIM * D_DIM);
    cvt(A1, W13b + (size_t)2 * F_DIM * D_DIM, (size_t)128 * D_DIM);
    cvt(A3, W13b + (size_t)2 * F_DIM * D_DIM + (size_t)128 * D_DIM, (size_t)128 * D_DIM);
    cvt(W2, W2b, (size_t)D_DIM * F_DIM);
    cvt(B1, B1b, (size_t)E_NUM * F_DIM * R_DIM);
    cvt(B3, B3b, (size_t)E_NUM * F_DIM * R_DIM);
    a2_transpose<<<dim3(F_DIM / 256, E_NUM), 256, 0, stream>>>(A2, A2t);

    router_kernel<<<N_TOK, 256, 0, stream>>>(x, gw, logits, ridx, rwt);
    zero_counts<<<1, 64, 0, stream>>>(counts);
    build_lists<<<N_TOK / 256, 256, 0, stream>>>(ridx, counts, lists);

    // fused GEMM: [base1 | base3 | l13] = x @ [W1;W3;A1;A3]^T  (bf16 out, 720 blocks)
    gemm_bf16_bt<<<dim3(N_TOK / 128, BN13 / 128), 256, 0, stream>>>(xb, W13b, (float*)base13,
                                                                    N_TOK, BN13, D_DIM, 1);

    act_v2b<<<dim3(NT, E_NUM, TC), 256, 0, stream>>>(base13, B1b, B3b,
                                                     lists, counts, rwt, sbuf);

    combine_kernel<<<(N_TOK * F_DIM / 8) / 256, 256, 0, stream>>>(sbuf, smixb);

    // l2 from sbuf + LoRA-down; writes out. Then split-K GEMM atomically adds W2 term.
    lora_down_v3<<<N_TOK, 256, 0, stream>>>(sbuf, A2t, ridx, B2, out);

    gemm_bt_splitk<<<dim3(N_TOK / 128, D_DIM / 128, 4), 256, 0, stream>>>(smixb, W2b, out,
                                                                          N_TOK, D_DIM, F_DIM,
                                                                          F_DIM / 4);
}